// Round 4
// baseline (227.770 us; speedup 1.0000x reference)
//
#include <hip/hip_runtime.h>
#include <hip/hip_fp16.h>

// ---------------------------------------------------------------------------
// GCN 2-layer forward: out = relu(A_hat @ relu(A_hat @ (X W1) + b1) W2 + b2)
// A_hat = D^-1/2 (A + I) D^-1/2.
// Normalization folded: g = dinv[row]*(X@W); agg_n = dinv[n]*(g[n]+sum g[src]).
// Pipeline: bin by dst>>6 -> sort_bins (per-bin LDS counting sort, once) ->
// gemm_mfma (layer-1) -> agg_gemm_fused (layer-1 agg + layer-2 GEMM in one
// block per bin; h1 lives only in LDS) -> agg_64.
// R15: fused h1: aggs near the ~3.3TB/s L2-miss-path floor; removed the h1
// HBM round-trip (25MB) + one dispatch.
// R16 (FAILED, reverted): direct global counting sort. scatter_edges wrote
// 112MB (full-line writeback per random u16: 1.6M x 64B) at ~1TB/s = 120us.
// Lesson: random fine-grained scatter costs ~64B/record of HBM writeback.
// R18 (FAILED, reverted): TILE 8192->2048 regressed 216->225us; bin_kernel is
// write-BW-bound, not fill-bound. TILE stays 8192.
// R19: depth-4 gather pipelining in agg_gemm_fused phase 1 and agg_64.
// Both were 2-deep MLP (2 loads in flight/lane) gathering ~700cy LLC-miss
// rows; agg_fused measured 2.87 of the 3.3TB/s miss-path floor. 4 loads
// issued back-to-back per iteration; agg_64's typical 32-edge segment now
// one depth-4 iteration per octet. Same per-lane accumulation order ->
// bitwise-identical output.
// Requires N <= 65536 (src packs into 16 bits).
// ---------------------------------------------------------------------------

#define TILE 8192      // edges per bin_kernel block
#define BIN_CAP 2560   // per-bin record capacity (mean 2046, sd ~45 -> 11 sigma)

typedef _Float16 half8 __attribute__((ext_vector_type(8)));
typedef float floatx4 __attribute__((ext_vector_type(4)));

__device__ __forceinline__ void acc8(float* ax, const uint4& u) {
    float2 f;
    f = __half22float2(*(const __half2*)&u.x); ax[0] += f.x; ax[1] += f.y;
    f = __half22float2(*(const __half2*)&u.y); ax[2] += f.x; ax[3] += f.y;
    f = __half22float2(*(const __half2*)&u.z); ax[4] += f.x; ax[5] += f.y;
    f = __half22float2(*(const __half2*)&u.w); ax[6] += f.x; ax[7] += f.y;
}

// ---- bin edges by dst>>6: rec = (d&63)<<16 | s ----
__global__ __launch_bounds__(512) void bin_kernel(const int* __restrict__ src,
                                                  const int* __restrict__ dst, int E,
                                                  int nbins,
                                                  int* __restrict__ binCnt,
                                                  unsigned* __restrict__ recs) {
    extern __shared__ int lds[];           // cnt[nbins] | gbase[nbins]
    int* cnt = lds;
    int* gbase = lds + nbins;
    int tid = threadIdx.x;
    for (int i = tid; i < nbins; i += 512) cnt[i] = 0;
    __syncthreads();

    int t0 = blockIdx.x * TILE;
    int tEnd = min(t0 + TILE, E);

    for (int e = t0 + tid; e < tEnd; e += 512)
        atomicAdd(&cnt[dst[e] >> 6], 1);
    __syncthreads();

    for (int i = tid; i < nbins; i += 512) {
        int c = cnt[i];
        gbase[i] = (c > 0) ? atomicAdd(&binCnt[i], c) : 0;
        cnt[i] = 0;                        // reuse as local cursor
    }
    __syncthreads();

    for (int e = t0 + tid; e < tEnd; e += 512) {
        int d = dst[e];
        int s = src[e];
        int b = d >> 6;
        int r = atomicAdd(&cnt[b], 1);
        int g = gbase[b] + r;
        if (g < BIN_CAP)
            recs[(size_t)b * BIN_CAP + g] = ((unsigned)(d & 63) << 16) | (unsigned)s;
    }
}

// ---- per-bin counting sort (once): sorted u16 lists + starts + dinv ----
__global__ __launch_bounds__(512) void sort_bins(const unsigned* __restrict__ recs,
                                                 const int* __restrict__ binCnt,
                                                 unsigned short* __restrict__ sortedG,
                                                 int* __restrict__ startG,
                                                 float* __restrict__ dinv, int N) {
    __shared__ unsigned short sorted[BIN_CAP];
    __shared__ int c64[64];
    __shared__ int start[65];
    __shared__ int cursor[64];
    int b = blockIdx.x, tid = threadIdx.x;
    int lane = tid & 63, wave = tid >> 6;

    if (tid < 64) c64[tid] = 0;
    __syncthreads();
    int cnt = min(binCnt[b], BIN_CAP);
    const unsigned* bin = recs + (size_t)b * BIN_CAP;

    for (int i = tid; i < cnt; i += 512)
        atomicAdd(&c64[bin[i] >> 16], 1);
    __syncthreads();

    if (wave == 0) {
        int c = c64[lane];
        int v = c;
        #pragma unroll
        for (int off = 1; off < 64; off <<= 1) {
            int t = __shfl_up(v, off);
            if (lane >= off) v += t;
        }
        start[lane] = v - c;
        cursor[lane] = v - c;
        startG[b * 65 + lane] = v - c;
        if (lane == 63) { start[64] = v; startG[b * 65 + 64] = v; }
        int n = (b << 6) + lane;
        if (n < N) dinv[n] = rsqrtf((float)(c + 1));   // +1 = self loop
    }
    __syncthreads();

    for (int i = tid; i < cnt; i += 512) {
        unsigned r = bin[i];
        int pos = atomicAdd(&cursor[r >> 16], 1);
        sorted[pos] = (unsigned short)(r & 0xFFFFu);
    }
    __syncthreads();
    unsigned short* sg = sortedG + (size_t)b * BIN_CAP;
    for (int i = tid; i < cnt; i += 512) sg[i] = sorted[i];
}

// ---- MFMA fp16 GEMM (layer 1): Y[r,:] = half( dinv[r] * (X[r,:] @ W) ) ----
template <int COLS, bool FP32IN>
__global__ __launch_bounds__(256) void gemm_mfma(const void* __restrict__ Xv,
                                                 const float* __restrict__ W,
                                                 const float* __restrict__ dinv,
                                                 __half* __restrict__ Y, int N) {
    constexpr int LDA = 136;               // halfs; 272B row stride, 16B aligned
    __shared__ __align__(16) _Float16 aT[64 * LDA];
    __shared__ __align__(16) _Float16 bT[COLS * LDA];

    int tid = threadIdx.x;
    int lane = tid & 63, wave = tid >> 6;
    int row0 = blockIdx.x * 64;

    for (int i = tid * 4; i < 64 * 128; i += 1024) {
        int r = i >> 7, k = i & 127;
        int gr = row0 + r;
        if (FP32IN) {
            float4 v = make_float4(0.f, 0.f, 0.f, 0.f);
            if (gr < N) v = *(const float4*)&((const float*)Xv)[(size_t)gr * 128 + k];
            __half2 p0 = __floats2half2_rn(v.x, v.y);
            __half2 p1 = __floats2half2_rn(v.z, v.w);
            *(uint2*)&aT[r * LDA + k] = make_uint2(*(uint*)&p0, *(uint*)&p1);
        } else {
            ushort4 u = make_ushort4(0, 0, 0, 0);
            if (gr < N) u = *(const ushort4*)&((const __half*)Xv)[(size_t)gr * 128 + k];
            *(ushort4*)&aT[r * LDA + k] = u;
        }
    }
    for (int i = tid; i < 128 * COLS; i += 256) {
        int k = i / COLS, n = i % COLS;
        bT[n * LDA + k] = (_Float16)W[i];
    }
    __syncthreads();

    constexpr int NT = COLS / 16;
    floatx4 acc[NT];
    #pragma unroll
    for (int t = 0; t < NT; t++) acc[t] = (floatx4){0.f, 0.f, 0.f, 0.f};

    int m = lane & 15, q = lane >> 4;
    const _Float16* arow = &aT[(wave * 16 + m) * LDA + q * 8];

    #pragma unroll
    for (int ks = 0; ks < 4; ks++) {
        half8 af = *(const half8*)&arow[ks * 32];
        #pragma unroll
        for (int t = 0; t < NT; t++) {
            half8 bf = *(const half8*)&bT[(t * 16 + m) * LDA + ks * 32 + q * 8];
            acc[t] = __builtin_amdgcn_mfma_f32_16x16x32_f16(af, bf, acc[t], 0, 0, 0);
        }
    }
    __syncthreads();

    float dv[4];
    #pragma unroll
    for (int r = 0; r < 4; r++) {
        int gr = row0 + wave * 16 + q * 4 + r;
        dv[r] = (gr < N) ? dinv[gr] : 0.0f;
    }
    #pragma unroll
    for (int t = 0; t < NT; t++)
        #pragma unroll
        for (int r = 0; r < 4; r++)
            aT[(wave * 16 + q * 4 + r) * LDA + t * 16 + m] = (_Float16)(dv[r] * acc[t][r]);
    __syncthreads();

    for (int i = tid; i < 64 * (COLS / 2); i += 256) {
        int r = i / (COLS / 2), c = i % (COLS / 2);
        int gr = row0 + r;
        if (gr < N)
            ((uint*)Y)[(size_t)gr * (COLS / 2) + c] = *(uint*)&aT[r * LDA + c * 2];
    }
}

// ---- FUSED: layer-1 aggregation (64-node bin) + layer-2 GEMM ----
// Phase 1: 8 waves x 8 rows, quad-of-lanes gathers (16B/lane, depth-4
// pipelined), shfl_xor reduce, relu'd h1 row -> LDS tile hT[64][LDH] (fp16).
// Phase 2: hT @ W2 via v_mfma_f32_16x16x32_f16 (16 tiles, 2 per wave),
// dinv-scaled fp16 epilogue -> Y2 (coalesced).
__global__ __launch_bounds__(512) void agg_gemm_fused(
        const __half* __restrict__ G,
        const unsigned short* __restrict__ sortedG,
        const int* __restrict__ startG,
        const float* __restrict__ dinv,
        const float* __restrict__ bias,     // b1
        const float* __restrict__ W2,       // [128][64] fp32
        __half* __restrict__ Y2, int N) {
    constexpr int LDH = 136;
    __shared__ unsigned short buf[BIN_CAP];
    __shared__ int st[65];
    __shared__ __align__(16) _Float16 hT[64 * LDH];   // h1 tile (rows x k)
    __shared__ __align__(16) _Float16 bT[64 * LDH];   // W2^T (cols x k)

    int b = blockIdx.x;
    int tid = threadIdx.x, lane = tid & 63, wave = tid >> 6;
    int ql = lane & 15, quad = lane >> 4;

    if (tid < 65) st[tid] = startG[b * 65 + tid];
    __syncthreads();
    int cnt = st[64];
    const unsigned short* sg = sortedG + (size_t)b * BIN_CAP;
    for (int i = tid; i < cnt; i += 512) buf[i] = sg[i];
    // stage W2^T: bT[n][k] = W2[k][n]
    for (int i = tid; i < 128 * 64; i += 512) {
        int k = i >> 6, n = i & 63;
        bT[n * LDH + k] = (_Float16)W2[i];
    }
    __syncthreads();

    // bias slice for this lane's 8 features
    float bb[8];
    #pragma unroll
    for (int k = 0; k < 4; k++) {
        float2 t = *(const float2*)&bias[ql * 8 + k * 2];
        bb[k * 2] = t.x; bb[k * 2 + 1] = t.y;
    }

    // ---- phase 1: aggregate 8 rows per wave into hT ----
    for (int rr = 0; rr < 8; rr++) {
        int row = wave * 8 + rr;
        int n = (b << 6) + row;
        if (n >= N) {
            if (quad == 0) {
                uint4 z = make_uint4(0, 0, 0, 0);
                *(uint4*)&hT[row * LDH + ql * 8] = z;
            }
            continue;
        }
        int jst = st[row], jen = st[row + 1];

        float ax[8] = {};
        int j = jst + quad;
        // depth-4: 4 independent row-gathers in flight before any convert
        for (; j + 12 < jen; j += 16) {
            int s0 = buf[j], s1 = buf[j + 4], s2 = buf[j + 8], s3 = buf[j + 12];
            uint4 u0 = *(const uint4*)&G[(size_t)s0 * 128 + ql * 8];
            uint4 u1 = *(const uint4*)&G[(size_t)s1 * 128 + ql * 8];
            uint4 u2 = *(const uint4*)&G[(size_t)s2 * 128 + ql * 8];
            uint4 u3 = *(const uint4*)&G[(size_t)s3 * 128 + ql * 8];
            acc8(ax, u0); acc8(ax, u1); acc8(ax, u2); acc8(ax, u3);
        }
        for (; j < jen; j += 4) {
            int s = buf[j];
            uint4 u = *(const uint4*)&G[(size_t)s * 128 + ql * 8];
            acc8(ax, u);
        }
        #pragma unroll
        for (int k = 0; k < 8; k++) {
            ax[k] += __shfl_xor(ax[k], 16);
            ax[k] += __shfl_xor(ax[k], 32);
        }
        if (quad == 0) {
            uint4 us = *(const uint4*)&G[(size_t)n * 128 + ql * 8];
            acc8(ax, us);
            float di = dinv[n];
            __half2 h[4];
            #pragma unroll
            for (int k = 0; k < 4; k++) {
                float o0 = fmaxf(fmaf(di, ax[k * 2],     bb[k * 2]),     0.0f);
                float o1 = fmaxf(fmaf(di, ax[k * 2 + 1], bb[k * 2 + 1]), 0.0f);
                h[k] = __floats2half2_rn(o0, o1);
            }
            *(uint4*)&hT[row * LDH + ql * 8] = *(uint4*)h;
        }
    }
    __syncthreads();

    // ---- phase 2: g2 = dinv * (hT @ W2), 64x64 out, 2 tiles per wave ----
    int m = lane & 15, q = lane >> 4;
    int mt = wave & 3, nt0 = (wave >> 2) * 2;
    floatx4 acc[2] = {(floatx4){0.f, 0.f, 0.f, 0.f}, (floatx4){0.f, 0.f, 0.f, 0.f}};
    const _Float16* arow = &hT[(mt * 16 + m) * LDH + q * 8];
    #pragma unroll
    for (int ks = 0; ks < 4; ks++) {
        half8 af = *(const half8*)&arow[ks * 32];
        #pragma unroll
        for (int t = 0; t < 2; t++) {
            half8 bf = *(const half8*)&bT[((nt0 + t) * 16 + m) * LDH + ks * 32 + q * 8];
            acc[t] = __builtin_amdgcn_mfma_f32_16x16x32_f16(af, bf, acc[t], 0, 0, 0);
        }
    }
    __syncthreads();                       // all MFMA reads of hT done

    float dv[4];
    #pragma unroll
    for (int r = 0; r < 4; r++) {
        int gr = (b << 6) + mt * 16 + q * 4 + r;
        dv[r] = (gr < N) ? dinv[gr] : 0.0f;
    }
    #pragma unroll
    for (int t = 0; t < 2; t++)
        #pragma unroll
        for (int r = 0; r < 4; r++)
            hT[(mt * 16 + q * 4 + r) * LDH + (nt0 + t) * 16 + m] = (_Float16)(dv[r] * acc[t][r]);
    __syncthreads();

    for (int i = tid; i < 64 * 32; i += 512) {
        int r = i >> 5, c = i & 31;        // c indexes half2
        int gr = (b << 6) + r;
        if (gr < N)
            ((uint*)Y2)[(size_t)gr * 32 + c] = *(uint*)&hT[r * LDH + c * 2];
    }
}

// ---- agg F=64 (layer 2): block (b, half) = 32 rows; octet scheme ----
// depth-4 gather: typical 32-edge segment = one iteration per octet.
__global__ __launch_bounds__(512) void agg_64(const __half* __restrict__ G,
                                              const unsigned short* __restrict__ sortedG,
                                              const int* __restrict__ startG,
                                              const float* __restrict__ dinv,
                                              const float* __restrict__ bias,
                                              float* __restrict__ out, int N) {
    __shared__ unsigned short buf[BIN_CAP];
    __shared__ int st[33];
    int b = blockIdx.x, half_ = blockIdx.y;
    int tid = threadIdx.x, lane = tid & 63, wave = tid >> 6;
    int ol = lane & 7, oct = lane >> 3;
    int r0 = half_ * 32;

    if (tid < 33) st[tid] = startG[b * 65 + r0 + tid];
    __syncthreads();
    int S0 = st[0], S1 = st[32];
    const unsigned short* sg = sortedG + (size_t)b * BIN_CAP;
    for (int i = tid; i < S1 - S0; i += 512) buf[i] = sg[S0 + i];
    __syncthreads();

    float bb[8];
    #pragma unroll
    for (int k = 0; k < 4; k++) {
        float2 t = *(const float2*)&bias[ol * 8 + k * 2];
        bb[k * 2] = t.x; bb[k * 2 + 1] = t.y;
    }

    for (int rr = 0; rr < 4; rr++) {
        int row = wave * 4 + rr;
        int n = (b << 6) + r0 + row;
        if (n >= N) continue;
        int jst = st[row] - S0, jen = st[row + 1] - S0;

        float ax[8] = {};
        int j = jst + oct;
        // depth-4: 4 independent row-gathers in flight before any convert
        for (; j + 24 < jen; j += 32) {
            int s0 = buf[j], s1 = buf[j + 8], s2 = buf[j + 16], s3 = buf[j + 24];
            uint4 u0 = *(const uint4*)&G[(size_t)s0 * 64 + ol * 8];
            uint4 u1 = *(const uint4*)&G[(size_t)s1 * 64 + ol * 8];
            uint4 u2 = *(const uint4*)&G[(size_t)s2 * 64 + ol * 8];
            uint4 u3 = *(const uint4*)&G[(size_t)s3 * 64 + ol * 8];
            acc8(ax, u0); acc8(ax, u1); acc8(ax, u2); acc8(ax, u3);
        }
        for (; j < jen; j += 8) {
            int s = buf[j];
            uint4 u = *(const uint4*)&G[(size_t)s * 64 + ol * 8];
            acc8(ax, u);
        }
        #pragma unroll
        for (int k = 0; k < 8; k++) {
            ax[k] += __shfl_xor(ax[k], 8);
            ax[k] += __shfl_xor(ax[k], 16);
            ax[k] += __shfl_xor(ax[k], 32);
        }
        if (oct < 2) {
            uint4 us = *(const uint4*)&G[(size_t)n * 64 + ol * 8];
            acc8(ax, us);
            float di = dinv[n];
            float o[8];
            #pragma unroll
            for (int k = 0; k < 8; k++)
                o[k] = fmaxf(fmaf(di, ax[k], bb[k]), 0.0f);
            if (oct == 0)
                *(float4*)&out[(size_t)n * 64 + ol * 8] = make_float4(o[0], o[1], o[2], o[3]);
            else
                *(float4*)&out[(size_t)n * 64 + ol * 8 + 4] = make_float4(o[4], o[5], o[6], o[7]);
        }
    }
}

extern "C" void kernel_launch(void* const* d_in, const int* in_sizes, int n_in,
                              void* d_out, int out_size, void* d_ws, size_t ws_size,
                              hipStream_t stream) {
    const float* x  = (const float*)d_in[0];
    const int*   ei = (const int*)d_in[1];
    const float* W1 = (const float*)d_in[2];
    const float* b1 = (const float*)d_in[3];
    const float* W2 = (const float*)d_in[4];
    const float* b2 = (const float*)d_in[5];
    float* out = (float*)d_out;

    const int HID  = in_sizes[3];          // 128
    const int F_IN = in_sizes[2] / HID;    // 128
    const int N    = in_sizes[0] / F_IN;   // 50000
    const int E    = in_sizes[1] / 2;      // 1.6M
    (void)n_in; (void)out_size; (void)ws_size; (void)F_IN;

    const int* src = ei;
    const int* dst = ei + E;

    const int nbins = (N + 63) >> 6;       // 782

    // ---- carve workspace ----
    char* p = (char*)d_ws;
    auto carve = [&](size_t bytes) { void* q = (void*)p; p += (bytes + 255) & ~(size_t)255; return q; };
    int*            binCnt  = (int*)           carve((size_t)nbins * 4);
    float*          dinv    = (float*)         carve((size_t)N * 4);
    unsigned*       recs    = (unsigned*)      carve((size_t)nbins * BIN_CAP * 4);
    unsigned short* sortedG = (unsigned short*)carve((size_t)nbins * BIN_CAP * 2);
    int*            startG  = (int*)           carve((size_t)nbins * 65 * 4);
    __half*         bufG    = (__half*)        carve((size_t)N * 128 * 2);  // g1 gather table
    __half*         bufG2   = (__half*)        carve((size_t)N * 64 * 2);   // g2 gather table

    hipMemsetAsync(binCnt, 0, (size_t)nbins * 4, stream);

    // ---- bin + single sort pass ----
    int numTiles = (E + TILE - 1) / TILE;
    size_t binLds = (size_t)nbins * 2 * 4;
    bin_kernel<<<numTiles, 512, binLds, stream>>>(src, dst, E, nbins, binCnt, recs);
    sort_bins<<<nbins, 512, 0, stream>>>(recs, binCnt, sortedG, startG, dinv, N);

    int gemmGrid = (N + 63) / 64;

    // ---- layer 1 GEMM ----
    gemm_mfma<128, true><<<gemmGrid, 256, 0, stream>>>(x, W1, dinv, bufG, N);

    // ---- fused: layer-1 agg + layer-2 GEMM (h1 stays in LDS) ----
    agg_gemm_fused<<<nbins, 512, 0, stream>>>(bufG, sortedG, startG, dinv, b1, W2, bufG2, N);

    // ---- layer 2 aggregation ----
    dim3 aggGrid(nbins, 2);
    agg_64<<<aggGrid, 512, 0, stream>>>(bufG2, sortedG, startG, dinv, b2, out, N);
}

// Round 5
// 205.211 us; speedup vs baseline: 1.1099x; 1.1099x over previous
//
#include <hip/hip_runtime.h>
#include <hip/hip_fp16.h>

// ---------------------------------------------------------------------------
// GCN 2-layer forward: out = relu(A_hat @ relu(A_hat @ (X W1) + b1) W2 + b2)
// A_hat = D^-1/2 (A + I) D^-1/2.
// Pipeline: bin_gemm (bin by dst>>6 FUSED with layer-1 GEMM; gemm blocks
// backfill CUs idle during the 196-block bin phase) -> sort_bins (per-bin LDS
// counting sort -> sortedG/startG/dinv) -> agg_gemm_fused (layer-1 agg with
// DEFERRED dinv[src] scaling + layer-2 GEMM; h1 in LDS) -> agg_64.
// R15: fused h1 (agg at ~3.3TB/s miss-path floor; h1 HBM round-trip removed).
// R16 (FAILED): global counting sort -> 112MB partial-line writeback @1TB/s.
// Lesson: random fine-grained scatter ~64B/record writeback.
// R18 (FAILED): TILE 8192->2048; bin_kernel is write-BW-bound not fill-bound.
// R19 (FAILED): manual depth-4 gather pipelining slowed aggs (54->65us);
// compiler's 2-deep schedule was better. Don't hand-pipeline loops already
// near their BW floor. Gather loops restored to 2-deep.
// R20: layer-1 table stored UNSCALED (gemm no longer needs dinv -> no dep on
// sort_bins); agg_gemm_fused applies dinv[src] per gathered row via fmaf
// (same VALU count as add; dinv L2-resident). Enables bin+gemm single-dispatch
// fusion: ~10us of gemm hidden under bin's idle CUs + one launch gap removed.
// Requires N <= 65536 (src packs into 16 bits).
// ---------------------------------------------------------------------------

#define TILE 8192      // edges per bin block
#define BIN_CAP 2560   // per-bin record capacity (mean 2046, sd ~45 -> 11 sigma)

typedef _Float16 half8 __attribute__((ext_vector_type(8)));
typedef float floatx4 __attribute__((ext_vector_type(4)));

// accumulate 8 fp16 features scaled by d: ax[k] += d * f[k]
__device__ __forceinline__ void accs8(float* ax, const uint4& u, float d) {
    float2 f;
    f = __half22float2(*(const __half2*)&u.x); ax[0] = fmaf(d, f.x, ax[0]); ax[1] = fmaf(d, f.y, ax[1]);
    f = __half22float2(*(const __half2*)&u.y); ax[2] = fmaf(d, f.x, ax[2]); ax[3] = fmaf(d, f.y, ax[3]);
    f = __half22float2(*(const __half2*)&u.z); ax[4] = fmaf(d, f.x, ax[4]); ax[5] = fmaf(d, f.y, ax[5]);
    f = __half22float2(*(const __half2*)&u.w); ax[6] = fmaf(d, f.x, ax[6]); ax[7] = fmaf(d, f.y, ax[7]);
}

// unscaled accumulate (agg_64 path: table is pre-scaled)
__device__ __forceinline__ void acc8(float* ax, const uint4& u) {
    float2 f;
    f = __half22float2(*(const __half2*)&u.x); ax[0] += f.x; ax[1] += f.y;
    f = __half22float2(*(const __half2*)&u.y); ax[2] += f.x; ax[3] += f.y;
    f = __half22float2(*(const __half2*)&u.z); ax[4] += f.x; ax[5] += f.y;
    f = __half22float2(*(const __half2*)&u.w); ax[6] += f.x; ax[7] += f.y;
}

// ---- FUSED: edge binning (blocks [0,numTiles)) + layer-1 GEMM (rest) ----
// bin: rec = (d&63)<<16 | s, per-bin chunks reserved via global atomics.
// gemm: Y[r,:] = half( X[r,:] @ W )   (UNSCALED; dinv deferred to consumer)
template <int COLS>
__global__ __launch_bounds__(512) void bin_gemm(
        const int* __restrict__ src, const int* __restrict__ dst, int E,
        int nbins, int numTiles,
        int* __restrict__ binCnt, unsigned* __restrict__ recs,
        const float* __restrict__ Xv, const float* __restrict__ W,
        __half* __restrict__ Y, int N) {
    constexpr int LDA = 136;               // halfs; 272B row stride, 16B aligned
    __shared__ __align__(16) _Float16 smem[(64 + COLS) * LDA];   // 52224B
    int tid = threadIdx.x;

    if (blockIdx.x < numTiles) {
        // ---------------- bin part (196 blocks) ----------------
        int* cnt = (int*)smem;             // [nbins]
        int* gbase = cnt + nbins;          // [nbins]
        for (int i = tid; i < nbins; i += 512) cnt[i] = 0;
        __syncthreads();

        int t0 = blockIdx.x * TILE;
        int tEnd = min(t0 + TILE, E);

        for (int e = t0 + tid; e < tEnd; e += 512)
            atomicAdd(&cnt[dst[e] >> 6], 1);
        __syncthreads();

        for (int i = tid; i < nbins; i += 512) {
            int c = cnt[i];
            gbase[i] = (c > 0) ? atomicAdd(&binCnt[i], c) : 0;
            cnt[i] = 0;                    // reuse as local cursor
        }
        __syncthreads();

        for (int e = t0 + tid; e < tEnd; e += 512) {
            int d = dst[e];
            int s = src[e];
            int b = d >> 6;
            int r = atomicAdd(&cnt[b], 1);
            int g = gbase[b] + r;
            if (g < BIN_CAP)
                recs[(size_t)b * BIN_CAP + g] = ((unsigned)(d & 63) << 16) | (unsigned)s;
        }
        return;
    }

    // ---------------- gemm part (782 blocks, backfills idle CUs) ----------
    int bid = blockIdx.x - numTiles;
    _Float16* aT = smem;                   // 64 x LDA
    _Float16* bT = smem + 64 * LDA;        // COLS x LDA
    int lane = tid & 63, wave = tid >> 6;
    int row0 = bid * 64;

    for (int i = tid * 4; i < 64 * 128; i += 2048) {
        int r = i >> 7, k = i & 127;
        int gr = row0 + r;
        float4 v = make_float4(0.f, 0.f, 0.f, 0.f);
        if (gr < N) v = *(const float4*)&Xv[(size_t)gr * 128 + k];
        __half2 p0 = __floats2half2_rn(v.x, v.y);
        __half2 p1 = __floats2half2_rn(v.z, v.w);
        *(uint2*)&aT[r * LDA + k] = make_uint2(*(uint*)&p0, *(uint*)&p1);
    }
    for (int i = tid; i < 128 * COLS; i += 512) {
        int k = i / COLS, n = i % COLS;
        bT[n * LDA + k] = (_Float16)W[i];
    }
    __syncthreads();

    constexpr int NT = COLS / 16;
    int m = lane & 15, q = lane >> 4;
    floatx4 acc[NT];
    if (wave < 4) {
        #pragma unroll
        for (int t = 0; t < NT; t++) acc[t] = (floatx4){0.f, 0.f, 0.f, 0.f};
        const _Float16* arow = &aT[(wave * 16 + m) * LDA + q * 8];
        #pragma unroll
        for (int ks = 0; ks < 4; ks++) {
            half8 af = *(const half8*)&arow[ks * 32];
            #pragma unroll
            for (int t = 0; t < NT; t++) {
                half8 bf = *(const half8*)&bT[(t * 16 + m) * LDA + ks * 32 + q * 8];
                acc[t] = __builtin_amdgcn_mfma_f32_16x16x32_f16(af, bf, acc[t], 0, 0, 0);
            }
        }
    }
    __syncthreads();

    if (wave < 4) {
        #pragma unroll
        for (int t = 0; t < NT; t++)
            #pragma unroll
            for (int r = 0; r < 4; r++)
                aT[(wave * 16 + q * 4 + r) * LDA + t * 16 + m] = (_Float16)acc[t][r];
    }
    __syncthreads();

    for (int i = tid; i < 64 * (COLS / 2); i += 512) {
        int r = i / (COLS / 2), c = i % (COLS / 2);
        int gr = row0 + r;
        if (gr < N)
            ((uint*)Y)[(size_t)gr * (COLS / 2) + c] = *(uint*)&aT[r * LDA + c * 2];
    }
}

// ---- per-bin counting sort (once): sorted u16 lists + starts + dinv ----
__global__ __launch_bounds__(512) void sort_bins(const unsigned* __restrict__ recs,
                                                 const int* __restrict__ binCnt,
                                                 unsigned short* __restrict__ sortedG,
                                                 int* __restrict__ startG,
                                                 float* __restrict__ dinv, int N) {
    __shared__ unsigned short sorted[BIN_CAP];
    __shared__ int c64[64];
    __shared__ int start[65];
    __shared__ int cursor[64];
    int b = blockIdx.x, tid = threadIdx.x;
    int lane = tid & 63, wave = tid >> 6;

    if (tid < 64) c64[tid] = 0;
    __syncthreads();
    int cnt = min(binCnt[b], BIN_CAP);
    const unsigned* bin = recs + (size_t)b * BIN_CAP;

    for (int i = tid; i < cnt; i += 512)
        atomicAdd(&c64[bin[i] >> 16], 1);
    __syncthreads();

    if (wave == 0) {
        int c = c64[lane];
        int v = c;
        #pragma unroll
        for (int off = 1; off < 64; off <<= 1) {
            int t = __shfl_up(v, off);
            if (lane >= off) v += t;
        }
        start[lane] = v - c;
        cursor[lane] = v - c;
        startG[b * 65 + lane] = v - c;
        if (lane == 63) { start[64] = v; startG[b * 65 + 64] = v; }
        int n = (b << 6) + lane;
        if (n < N) dinv[n] = rsqrtf((float)(c + 1));   // +1 = self loop
    }
    __syncthreads();

    for (int i = tid; i < cnt; i += 512) {
        unsigned r = bin[i];
        int pos = atomicAdd(&cursor[r >> 16], 1);
        sorted[pos] = (unsigned short)(r & 0xFFFFu);
    }
    __syncthreads();
    unsigned short* sg = sortedG + (size_t)b * BIN_CAP;
    for (int i = tid; i < cnt; i += 512) sg[i] = sorted[i];
}

// ---- FUSED: layer-1 aggregation (64-node bin) + layer-2 GEMM ----
// Phase 1: 8 waves x 8 rows, quad-of-lanes gathers (16B/lane, 2-deep),
// dinv[src] applied via fmaf (table unscaled, R20), shfl_xor reduce,
// relu'd h1 row -> LDS tile hT[64][LDH] (fp16).
// Phase 2: hT @ W2 via v_mfma_f32_16x16x32_f16, dinv-scaled fp16 epilogue.
__global__ __launch_bounds__(512) void agg_gemm_fused(
        const __half* __restrict__ G,
        const unsigned short* __restrict__ sortedG,
        const int* __restrict__ startG,
        const float* __restrict__ dinv,
        const float* __restrict__ bias,     // b1
        const float* __restrict__ W2,       // [128][64] fp32
        __half* __restrict__ Y2, int N) {
    constexpr int LDH = 136;
    __shared__ unsigned short buf[BIN_CAP];
    __shared__ int st[65];
    __shared__ __align__(16) _Float16 hT[64 * LDH];   // h1 tile (rows x k)
    __shared__ __align__(16) _Float16 bT[64 * LDH];   // W2^T (cols x k)

    int b = blockIdx.x;
    int tid = threadIdx.x, lane = tid & 63, wave = tid >> 6;
    int ql = lane & 15, quad = lane >> 4;

    if (tid < 65) st[tid] = startG[b * 65 + tid];
    __syncthreads();
    int cnt = st[64];
    const unsigned short* sg = sortedG + (size_t)b * BIN_CAP;
    for (int i = tid; i < cnt; i += 512) buf[i] = sg[i];
    // stage W2^T: bT[n][k] = W2[k][n]
    for (int i = tid; i < 128 * 64; i += 512) {
        int k = i >> 6, n = i & 63;
        bT[n * LDH + k] = (_Float16)W2[i];
    }
    __syncthreads();

    // bias slice for this lane's 8 features
    float bb[8];
    #pragma unroll
    for (int k = 0; k < 4; k++) {
        float2 t = *(const float2*)&bias[ql * 8 + k * 2];
        bb[k * 2] = t.x; bb[k * 2 + 1] = t.y;
    }

    // ---- phase 1: aggregate 8 rows per wave into hT ----
    for (int rr = 0; rr < 8; rr++) {
        int row = wave * 8 + rr;
        int n = (b << 6) + row;
        if (n >= N) {
            if (quad == 0) {
                uint4 z = make_uint4(0, 0, 0, 0);
                *(uint4*)&hT[row * LDH + ql * 8] = z;
            }
            continue;
        }
        int jst = st[row], jen = st[row + 1];

        float ax[8] = {};
        int j = jst + quad;
        for (; j + 4 < jen; j += 8) {
            int sA = buf[j], sB = buf[j + 4];
            uint4 uA = *(const uint4*)&G[(size_t)sA * 128 + ql * 8];
            uint4 uB = *(const uint4*)&G[(size_t)sB * 128 + ql * 8];
            float dA = dinv[sA], dB = dinv[sB];
            accs8(ax, uA, dA);
            accs8(ax, uB, dB);
        }
        for (; j < jen; j += 4) {
            int s = buf[j];
            uint4 u = *(const uint4*)&G[(size_t)s * 128 + ql * 8];
            accs8(ax, u, dinv[s]);
        }
        #pragma unroll
        for (int k = 0; k < 8; k++) {
            ax[k] += __shfl_xor(ax[k], 16);
            ax[k] += __shfl_xor(ax[k], 32);
        }
        if (quad == 0) {
            uint4 us = *(const uint4*)&G[(size_t)n * 128 + ql * 8];
            float di = dinv[n];
            accs8(ax, us, di);             // self loop, scaled by dinv[n]
            __half2 h[4];
            #pragma unroll
            for (int k = 0; k < 4; k++) {
                float o0 = fmaxf(fmaf(di, ax[k * 2],     bb[k * 2]),     0.0f);
                float o1 = fmaxf(fmaf(di, ax[k * 2 + 1], bb[k * 2 + 1]), 0.0f);
                h[k] = __floats2half2_rn(o0, o1);
            }
            *(uint4*)&hT[row * LDH + ql * 8] = *(uint4*)h;
        }
    }
    __syncthreads();

    // ---- phase 2: g2 = dinv * (hT @ W2), 64x64 out, 2 tiles per wave ----
    int m = lane & 15, q = lane >> 4;
    int mt = wave & 3, nt0 = (wave >> 2) * 2;
    floatx4 acc[2] = {(floatx4){0.f, 0.f, 0.f, 0.f}, (floatx4){0.f, 0.f, 0.f, 0.f}};
    const _Float16* arow = &hT[(mt * 16 + m) * LDH + q * 8];
    #pragma unroll
    for (int ks = 0; ks < 4; ks++) {
        half8 af = *(const half8*)&arow[ks * 32];
        #pragma unroll
        for (int t = 0; t < 2; t++) {
            half8 bf = *(const half8*)&bT[((nt0 + t) * 16 + m) * LDH + ks * 32 + q * 8];
            acc[t] = __builtin_amdgcn_mfma_f32_16x16x32_f16(af, bf, acc[t], 0, 0, 0);
        }
    }
    __syncthreads();                       // all MFMA reads of hT done

    float dv[4];
    #pragma unroll
    for (int r = 0; r < 4; r++) {
        int gr = (b << 6) + mt * 16 + q * 4 + r;
        dv[r] = (gr < N) ? dinv[gr] : 0.0f;
    }
    #pragma unroll
    for (int t = 0; t < 2; t++)
        #pragma unroll
        for (int r = 0; r < 4; r++)
            hT[(mt * 16 + q * 4 + r) * LDH + (nt0 + t) * 16 + m] = (_Float16)(dv[r] * acc[t][r]);
    __syncthreads();

    for (int i = tid; i < 64 * 32; i += 512) {
        int r = i >> 5, c = i & 31;        // c indexes half2
        int gr = (b << 6) + r;
        if (gr < N)
            ((uint*)Y2)[(size_t)gr * 32 + c] = *(uint*)&hT[r * LDH + c * 2];
    }
}

// ---- agg F=64 (layer 2): block (b, half) = 32 rows; octet scheme ----
__global__ __launch_bounds__(512) void agg_64(const __half* __restrict__ G,
                                              const unsigned short* __restrict__ sortedG,
                                              const int* __restrict__ startG,
                                              const float* __restrict__ dinv,
                                              const float* __restrict__ bias,
                                              float* __restrict__ out, int N) {
    __shared__ unsigned short buf[BIN_CAP];
    __shared__ int st[33];
    int b = blockIdx.x, half_ = blockIdx.y;
    int tid = threadIdx.x, lane = tid & 63, wave = tid >> 6;
    int ol = lane & 7, oct = lane >> 3;
    int r0 = half_ * 32;

    if (tid < 33) st[tid] = startG[b * 65 + r0 + tid];
    __syncthreads();
    int S0 = st[0], S1 = st[32];
    const unsigned short* sg = sortedG + (size_t)b * BIN_CAP;
    for (int i = tid; i < S1 - S0; i += 512) buf[i] = sg[S0 + i];
    __syncthreads();

    float bb[8];
    #pragma unroll
    for (int k = 0; k < 4; k++) {
        float2 t = *(const float2*)&bias[ol * 8 + k * 2];
        bb[k * 2] = t.x; bb[k * 2 + 1] = t.y;
    }

    for (int rr = 0; rr < 4; rr++) {
        int row = wave * 4 + rr;
        int n = (b << 6) + r0 + row;
        if (n >= N) continue;
        int jst = st[row] - S0, jen = st[row + 1] - S0;

        float ax[8] = {};
        int j = jst + oct;
        for (; j + 8 < jen; j += 16) {
            int sA = buf[j], sB = buf[j + 8];
            uint4 uA = *(const uint4*)&G[(size_t)sA * 64 + ol * 8];
            uint4 uB = *(const uint4*)&G[(size_t)sB * 64 + ol * 8];
            acc8(ax, uA);
            acc8(ax, uB);
        }
        for (; j < jen; j += 8) {
            int s = buf[j];
            uint4 u = *(const uint4*)&G[(size_t)s * 64 + ol * 8];
            acc8(ax, u);
        }
        #pragma unroll
        for (int k = 0; k < 8; k++) {
            ax[k] += __shfl_xor(ax[k], 8);
            ax[k] += __shfl_xor(ax[k], 16);
            ax[k] += __shfl_xor(ax[k], 32);
        }
        if (oct < 2) {
            uint4 us = *(const uint4*)&G[(size_t)n * 64 + ol * 8];
            acc8(ax, us);
            float di = dinv[n];
            float o[8];
            #pragma unroll
            for (int k = 0; k < 8; k++)
                o[k] = fmaxf(fmaf(di, ax[k], bb[k]), 0.0f);
            if (oct == 0)
                *(float4*)&out[(size_t)n * 64 + ol * 8] = make_float4(o[0], o[1], o[2], o[3]);
            else
                *(float4*)&out[(size_t)n * 64 + ol * 8 + 4] = make_float4(o[4], o[5], o[6], o[7]);
        }
    }
}

extern "C" void kernel_launch(void* const* d_in, const int* in_sizes, int n_in,
                              void* d_out, int out_size, void* d_ws, size_t ws_size,
                              hipStream_t stream) {
    const float* x  = (const float*)d_in[0];
    const int*   ei = (const int*)d_in[1];
    const float* W1 = (const float*)d_in[2];
    const float* b1 = (const float*)d_in[3];
    const float* W2 = (const float*)d_in[4];
    const float* b2 = (const float*)d_in[5];
    float* out = (float*)d_out;

    const int HID  = in_sizes[3];          // 128
    const int F_IN = in_sizes[2] / HID;    // 128
    const int N    = in_sizes[0] / F_IN;   // 50000
    const int E    = in_sizes[1] / 2;      // 1.6M
    (void)n_in; (void)out_size; (void)ws_size; (void)F_IN;

    const int* src = ei;
    const int* dst = ei + E;

    const int nbins = (N + 63) >> 6;       // 782

    // ---- carve workspace ----
    char* p = (char*)d_ws;
    auto carve = [&](size_t bytes) { void* q = (void*)p; p += (bytes + 255) & ~(size_t)255; return q; };
    int*            binCnt  = (int*)           carve((size_t)nbins * 4);
    float*          dinv    = (float*)         carve((size_t)N * 4);
    unsigned*       recs    = (unsigned*)      carve((size_t)nbins * BIN_CAP * 4);
    unsigned short* sortedG = (unsigned short*)carve((size_t)nbins * BIN_CAP * 2);
    int*            startG  = (int*)           carve((size_t)nbins * 65 * 4);
    __half*         bufG    = (__half*)        carve((size_t)N * 128 * 2);  // g1 gather table (UNSCALED, R20)
    __half*         bufG2   = (__half*)        carve((size_t)N * 64 * 2);   // g2 gather table (pre-scaled)

    hipMemsetAsync(binCnt, 0, (size_t)nbins * 4, stream);

    // ---- fused bin + layer-1 GEMM (gemm blocks backfill idle CUs) ----
    int numTiles = (E + TILE - 1) / TILE;  // 196
    int gemmGrid = (N + 63) / 64;          // 782
    bin_gemm<128><<<numTiles + gemmGrid, 512, 0, stream>>>(
        src, dst, E, nbins, numTiles, binCnt, recs, x, W1, bufG, N);

    // ---- per-bin sort (also produces dinv for the agg kernels) ----
    sort_bins<<<nbins, 512, 0, stream>>>(recs, binCnt, sortedG, startG, dinv, N);

    // ---- fused: layer-1 agg (deferred dinv) + layer-2 GEMM ----
    agg_gemm_fused<<<nbins, 512, 0, stream>>>(bufG, sortedG, startG, dinv, b1, W2, bufG2, N);

    // ---- layer 2 aggregation ----
    dim3 aggGrid(nbins, 2);
    agg_64<<<aggGrid, 512, 0, stream>>>(bufG2, sortedG, startG, dinv, b2, out, N);
}